// Round 8
// baseline (119.623 us; speedup 1.0000x reference)
//
#include <hip/hip_runtime.h>
#include <hip/hip_bf16.h>

// Problem constants
constexpr int BATCH = 4;
constexpr int SEQ   = 4096;
constexpr int DIM   = 128;   // head size

// Split-KV config: KV tiles are 64 keys; CHUNK tiles per split block.
constexpr int CHUNK       = 8;                    // 512 keys per block
constexpr int TASKS_PER_B = 288;                  // sum_qt ceil((qt+1)/8)
constexpr int SLOT_F32    = 64 + 64 + 64 * 128;   // m[64], l[64], O[64][128]
constexpr size_t QKV_BYTES  = (size_t)3 * BATCH * SEQ * DIM * 2;
constexpr size_t PART_BYTES = (size_t)BATCH * TASKS_PER_B * SLOT_F32 * 4;

typedef __bf16 bf16x8 __attribute__((ext_vector_type(8)));
typedef float  f32x4  __attribute__((ext_vector_type(4)));

// ---------------------------------------------------------------------------
// Kernel 1: QKV projection. Grid (128, 3). 256 thr = 4 waves, 128 rows each.
// ---------------------------------------------------------------------------
__global__ __launch_bounds__(256) void qkv_proj(
    const float* __restrict__ x,
    const float* __restrict__ Wq, const float* __restrict__ Wk,
    const float* __restrict__ Wv,
    __bf16* __restrict__ q, __bf16* __restrict__ k, __bf16* __restrict__ v)
{
    __shared__ __align__(16) __bf16 Xl[128][136];
    __shared__ __align__(16) __bf16 Wt[128][136];   // W transposed: Wt[d][c]

    const int t    = threadIdx.x;
    const int lane = t & 63;
    const int w    = t >> 6;
    const int l15  = lane & 15;
    const int l4   = lane >> 4;
    const int rowblk = blockIdx.x * 128;
    const int m      = blockIdx.y;

    const float* W  = (m == 0) ? Wq : (m == 1) ? Wk : Wv;
    __bf16*      op = (m == 0) ? q  : (m == 1) ? k  : v;

    #pragma unroll
    for (int i = 0; i < 16; ++i) {
        int idx = i * 256 + t;
        int r   = idx >> 5;
        int c4  = (idx & 31) << 2;
        float4 f = *(const float4*)(x + (size_t)(rowblk + r) * DIM + c4);
        __bf16* dst = &Xl[r][c4];
        dst[0] = (__bf16)f.x; dst[1] = (__bf16)f.y;
        dst[2] = (__bf16)f.z; dst[3] = (__bf16)f.w;
    }
    #pragma unroll
    for (int i = 0; i < 16; ++i) {
        int idx = i * 256 + t;
        int r   = idx >> 5;
        int c4  = (idx & 31) << 2;
        float4 f = *(const float4*)(W + (size_t)r * DIM + c4);
        Wt[c4 + 0][r] = (__bf16)f.x;
        Wt[c4 + 1][r] = (__bf16)f.y;
        Wt[c4 + 2][r] = (__bf16)f.z;
        Wt[c4 + 3][r] = (__bf16)f.w;
    }
    __syncthreads();

    f32x4 acc[2][8];
    #pragma unroll
    for (int a = 0; a < 2; ++a)
        #pragma unroll
        for (int cf = 0; cf < 8; ++cf) acc[a][cf] = (f32x4){0.f, 0.f, 0.f, 0.f};

    #pragma unroll
    for (int kc = 0; kc < 4; ++kc) {
        bf16x8 af0 = *(const bf16x8*)&Xl[w * 32 +      l15][kc * 32 + l4 * 8];
        bf16x8 af1 = *(const bf16x8*)&Xl[w * 32 + 16 + l15][kc * 32 + l4 * 8];
        #pragma unroll
        for (int cf = 0; cf < 8; ++cf) {
            bf16x8 bfr = *(const bf16x8*)&Wt[cf * 16 + l15][kc * 32 + l4 * 8];
            acc[0][cf] = __builtin_amdgcn_mfma_f32_16x16x32_bf16(af0, bfr, acc[0][cf], 0, 0, 0);
            acc[1][cf] = __builtin_amdgcn_mfma_f32_16x16x32_bf16(af1, bfr, acc[1][cf], 0, 0, 0);
        }
    }

    #pragma unroll
    for (int a = 0; a < 2; ++a)
        #pragma unroll
        for (int cf = 0; cf < 8; ++cf)
            #pragma unroll
            for (int r2 = 0; r2 < 4; ++r2) {
                int row = rowblk + w * 32 + a * 16 + l4 * 4 + r2;
                int col = cf * 16 + l15;
                op[(size_t)row * DIM + col] = (__bf16)acc[a][cf][r2];
            }
}

// ---------------------------------------------------------------------------
// Kernel 2: causal flash attention, split-KV. R2's proven structure verbatim
// (K LDS-staged padded, V transposed+XOR-swizzled scalar writes, P per-wave
// LDS round-trip, 4-row softmax) with exactly two additions:
//  (1) exp2-domain softmax (scale*log2e folded into logits),
//  (2) T14 reg-prefetch: next tile's K/V global loads issued after QK^T,
//      staged regs->LDS at the top of the next iteration.
// ---------------------------------------------------------------------------
template <bool SPLIT>
__global__ __launch_bounds__(256) void attn(
    const __bf16* __restrict__ q, const __bf16* __restrict__ k,
    const __bf16* __restrict__ v, float* __restrict__ out,
    float* __restrict__ part)
{
    __shared__ __align__(16) __bf16 Kl[64][136];
    __shared__ __align__(16) __bf16 Vt[128][72];
    __shared__ __align__(16) __bf16 Pl[4][16][72];

    const int t    = threadIdx.x;
    const int lane = t & 63;
    const int w    = t >> 6;
    const int l15  = lane & 15;
    const int l4   = lane >> 4;
    const int b    = blockIdx.y;

    int qt, chunk, nch, slot = 0;
    if (SPLIT) {
        int j = blockIdx.x;                 // 0..287
        int g = 0;
        while (g < 7 && j >= 4 * (g + 1) * (g + 2)) ++g;
        int r = j - 4 * g * (g + 1);
        nch   = g + 1;
        qt    = 8 * g + r / nch;
        chunk = r - (r / nch) * nch;
        slot  = b * TASKS_PER_B + j;
    } else {
        qt = blockIdx.x; chunk = 0; nch = 1;
    }
    const int qb0 = qt * 64;
    const int jt0 = chunk * CHUNK;
    const int jtE = SPLIT ? min(jt0 + CHUNK, qt + 1) : qt + 1;
    const size_t base = (size_t)b * SEQ * DIM;

    // staging geometry (same 16B/thread pattern for K and V)
    const int rr = t >> 4;             // 0..15
    const int c  = (t & 15) * 8;       // d base, 0..120

    // Q fragments (A-operand layout: row = l15, k = l4*8 + j + 32*dc)
    bf16x8 qf[4];
    {
        const __bf16* qrow = q + base + (size_t)(qb0 + w * 16 + l15) * DIM;
        #pragma unroll
        for (int dc = 0; dc < 4; ++dc)
            qf[dc] = *(const bf16x8*)(qrow + dc * 32 + l4 * 8);
    }

    f32x4 o[8];
    #pragma unroll
    for (int i = 0; i < 8; ++i) o[i] = (f32x4){0.f, 0.f, 0.f, 0.f};
    float mr[4], lr[4];
    #pragma unroll
    for (int r = 0; r < 4; ++r) { mr[r] = -INFINITY; lr[r] = 0.f; }

    // logits scaled by (1/sqrt(128))*log2(e); softmax in exp2 domain
    const float kScaleLog2e = 0.1275174454976458f;

    // ---- prologue: first K and V tiles into regs ----
    int4   kreg[4];
    bf16x8 vreg[4];
    {
        const __bf16* kg = k + base + (size_t)jt0 * 64 * DIM;
        const __bf16* vg = v + base + (size_t)jt0 * 64 * DIM;
        #pragma unroll
        for (int i = 0; i < 4; ++i) {
            int row = i * 16 + rr;
            kreg[i] = *(const int4*)(kg + (size_t)row * DIM + c);
            vreg[i] = *(const bf16x8*)(vg + (size_t)row * DIM + c);
        }
    }

    for (int jt = jt0; jt < jtE; ++jt) {
        __syncthreads();   // all waves done reading Kl/Vt of previous tile

        // ---- stage K (regs->LDS, padded) and V (regs->Vt, transposed) ----
        #pragma unroll
        for (int i = 0; i < 4; ++i) {
            int row = i * 16 + rr;   // key index 0..63
            *(int4*)&Kl[row][c] = kreg[i];
            #pragma unroll
            for (int j = 0; j < 8; ++j) {
                int cc  = c + j;  // d index
                int col = (((row >> 3) ^ ((cc >> 3) & 7)) << 3) | (row & 7);
                Vt[cc][col] = vreg[i][j];
            }
        }
        __syncthreads();

        // ---- S = Q K^T (16x64 per wave) ----
        f32x4 s[4];
        #pragma unroll
        for (int kc = 0; kc < 4; ++kc) {
            f32x4 acc = (f32x4){0.f, 0.f, 0.f, 0.f};
            #pragma unroll
            for (int dc = 0; dc < 4; ++dc) {
                bf16x8 kf = *(const bf16x8*)&Kl[kc * 16 + l15][dc * 32 + l4 * 8];
                acc = __builtin_amdgcn_mfma_f32_16x16x32_bf16(qf[dc], kf, acc, 0, 0, 0);
            }
            s[kc] = acc;
        }

        // ---- prefetch next tile's K/V into regs (hides under softmax+PV) ----
        if (jt + 1 < jtE) {
            const __bf16* kg = k + base + (size_t)(jt + 1) * 64 * DIM;
            const __bf16* vg = v + base + (size_t)(jt + 1) * 64 * DIM;
            #pragma unroll
            for (int i = 0; i < 4; ++i) {
                int row = i * 16 + rr;
                kreg[i] = *(const int4*)(kg + (size_t)row * DIM + c);
                vreg[i] = *(const bf16x8*)(vg + (size_t)row * DIM + c);
            }
        }

        // ---- scale(+log2e) + causal mask + online softmax (exp2 domain) ----
        const bool diag = (jt == qt);
        float rowmax[4];
        #pragma unroll
        for (int r = 0; r < 4; ++r) rowmax[r] = -INFINITY;
        #pragma unroll
        for (int kc = 0; kc < 4; ++kc) {
            int key = jt * 64 + kc * 16 + l15;
            #pragma unroll
            for (int r = 0; r < 4; ++r) {
                float sv = s[kc][r] * kScaleLog2e;
                if (diag) {
                    int qrow = qb0 + w * 16 + l4 * 4 + r;
                    if (key > qrow) sv = -INFINITY;
                }
                s[kc][r] = sv;
                rowmax[r] = fmaxf(rowmax[r], sv);
            }
        }
        #pragma unroll
        for (int r = 0; r < 4; ++r) {
            float x2 = rowmax[r];
            x2 = fmaxf(x2, __shfl_xor(x2, 1));
            x2 = fmaxf(x2, __shfl_xor(x2, 2));
            x2 = fmaxf(x2, __shfl_xor(x2, 4));
            x2 = fmaxf(x2, __shfl_xor(x2, 8));
            rowmax[r] = x2;
        }
        float alpha[4];
        #pragma unroll
        for (int r = 0; r < 4; ++r) {
            float mnew = fmaxf(mr[r], rowmax[r]);
            alpha[r]   = exp2f(mr[r] - mnew);
            mr[r]      = mnew;
        }
        float rowsum[4] = {0.f, 0.f, 0.f, 0.f};
        #pragma unroll
        for (int kc = 0; kc < 4; ++kc)
            #pragma unroll
            for (int r = 0; r < 4; ++r) {
                float p = exp2f(s[kc][r] - mr[r]);
                s[kc][r] = p;
                rowsum[r] += p;
            }
        #pragma unroll
        for (int r = 0; r < 4; ++r) {
            float x2 = rowsum[r];
            x2 += __shfl_xor(x2, 1);
            x2 += __shfl_xor(x2, 2);
            x2 += __shfl_xor(x2, 4);
            x2 += __shfl_xor(x2, 8);
            lr[r] = lr[r] * alpha[r] + x2;
        }
        #pragma unroll
        for (int df = 0; df < 8; ++df)
            #pragma unroll
            for (int r = 0; r < 4; ++r) o[df][r] *= alpha[r];

        // ---- P -> bf16 A-fragment layout via per-wave LDS ----
        #pragma unroll
        for (int kc = 0; kc < 4; ++kc)
            #pragma unroll
            for (int r = 0; r < 4; ++r)
                Pl[w][l4 * 4 + r][kc * 16 + l15] = (__bf16)s[kc][r];

        // ---- O += P V ----
        #pragma unroll
        for (int pc = 0; pc < 2; ++pc) {
            bf16x8 pa = *(const bf16x8*)&Pl[w][l15][pc * 32 + l4 * 8];
            #pragma unroll
            for (int df = 0; df < 8; ++df) {
                int cc  = df * 16 + l15;
                int kch = (pc * 4 + l4) ^ ((cc >> 3) & 7);
                bf16x8 vf = *(const bf16x8*)&Vt[cc][kch * 8];
                o[df] = __builtin_amdgcn_mfma_f32_16x16x32_bf16(pa, vf, o[df], 0, 0, 0);
            }
        }
    }

    if (!SPLIT || nch == 1) {
        float inv[4];
        #pragma unroll
        for (int r = 0; r < 4; ++r) inv[r] = 1.0f / lr[r];
        float* op = out + base;
        #pragma unroll
        for (int df = 0; df < 8; ++df)
            #pragma unroll
            for (int r = 0; r < 4; ++r) {
                int row = qb0 + w * 16 + l4 * 4 + r;
                op[(size_t)row * DIM + df * 16 + l15] = o[df][r] * inv[r];
            }
    } else {
        float* sp = part + (size_t)slot * SLOT_F32;
        #pragma unroll
        for (int r = 0; r < 4; ++r) {
            int rl = w * 16 + l4 * 4 + r;
            if (l15 == 0) { sp[rl] = mr[r]; sp[64 + rl] = lr[r]; }
        }
        #pragma unroll
        for (int df = 0; df < 8; ++df)
            #pragma unroll
            for (int r = 0; r < 4; ++r) {
                int rl = w * 16 + l4 * 4 + r;
                sp[128 + (size_t)rl * 128 + df * 16 + l15] = o[df][r];
            }
    }
}

// ---------------------------------------------------------------------------
// Kernel 3: combine partials for qt >= 8. Grid (56, B), 256 threads.
// m/l are in the exp2 domain -- weights use exp2f.
// ---------------------------------------------------------------------------
__global__ __launch_bounds__(256) void combine(
    const float* __restrict__ part, float* __restrict__ out)
{
    const int qt  = blockIdx.x + 8;
    const int b   = blockIdx.y;
    const int g   = qt >> 3;
    const int nch = g + 1;
    const int slot0 = b * TASKS_PER_B + 4 * g * (g + 1) + (qt & 7) * nch;

    const int t   = threadIdx.x;
    const int row = t >> 2;
    const int c0  = (t & 3) * 32;

    float M = -INFINITY;
    for (int c = 0; c < nch; ++c)
        M = fmaxf(M, part[(size_t)(slot0 + c) * SLOT_F32 + row]);
    float L = 0.f;
    for (int c = 0; c < nch; ++c) {
        const float* sp = part + (size_t)(slot0 + c) * SLOT_F32;
        L += sp[64 + row] * exp2f(sp[row] - M);
    }

    float4 acc[8];
    #pragma unroll
    for (int i = 0; i < 8; ++i) acc[i] = (float4){0.f, 0.f, 0.f, 0.f};
    for (int c = 0; c < nch; ++c) {
        const float* sp = part + (size_t)(slot0 + c) * SLOT_F32;
        float wgt = exp2f(sp[row] - M);
        const float* op = sp + 128 + (size_t)row * 128 + c0;
        #pragma unroll
        for (int i = 0; i < 8; ++i) {
            float4 f = *(const float4*)(op + i * 4);
            acc[i].x += wgt * f.x; acc[i].y += wgt * f.y;
            acc[i].z += wgt * f.z; acc[i].w += wgt * f.w;
        }
    }
    float invL = 1.0f / L;
    float* o = out + ((size_t)b * SEQ + (size_t)qt * 64 + row) * DIM + c0;
    #pragma unroll
    for (int i = 0; i < 8; ++i) {
        float4 f;
        f.x = acc[i].x * invL; f.y = acc[i].y * invL;
        f.z = acc[i].z * invL; f.w = acc[i].w * invL;
        *(float4*)(o + i * 4) = f;
    }
}

// ---------------------------------------------------------------------------
extern "C" void kernel_launch(void* const* d_in, const int* in_sizes, int n_in,
                              void* d_out, int out_size, void* d_ws, size_t ws_size,
                              hipStream_t stream) {
    const float* x  = (const float*)d_in[0];
    const float* Wq = (const float*)d_in[1];
    const float* Wk = (const float*)d_in[2];
    const float* Wv = (const float*)d_in[3];
    float* out = (float*)d_out;

    __bf16* qw = (__bf16*)d_ws;
    __bf16* kw = qw + (size_t)BATCH * SEQ * DIM;
    __bf16* vw = kw + (size_t)BATCH * SEQ * DIM;
    float*  part = (float*)((char*)d_ws + QKV_BYTES);

    qkv_proj<<<dim3(BATCH * SEQ / 128, 3), 256, 0, stream>>>(x, Wq, Wk, Wv, qw, kw, vw);

    if (ws_size >= QKV_BYTES + PART_BYTES) {
        attn<true><<<dim3(TASKS_PER_B, BATCH), 256, 0, stream>>>(qw, kw, vw, out, part);
        combine<<<dim3(56, BATCH), 256, 0, stream>>>(part, out);
    } else {
        attn<false><<<dim3(SEQ / 64, BATCH), 256, 0, stream>>>(qw, kw, vw, out, part);
    }
}

// Round 9
// 108.335 us; speedup vs baseline: 1.1042x; 1.1042x over previous
//
#include <hip/hip_runtime.h>
#include <hip/hip_bf16.h>

// Problem constants
constexpr int BATCH = 4;
constexpr int SEQ   = 4096;
constexpr int DIM   = 128;   // head size

// Split-KV: KV tiles are 64 keys; CHUNK tiles per split block (templated).
// tasks/batch for chunk c: NG=64/c groups; sum = c*NG*(NG+1)/2.
constexpr int SLOT_F32 = 64 + 64 + 64 * 128;   // m[64], l[64], O[64][128]
constexpr size_t QKV_BYTES = (size_t)3 * BATCH * SEQ * DIM * 2;

constexpr int tasks_per_b(int chunk) {
    return chunk * (64 / chunk) * (64 / chunk + 1) / 2;
}
constexpr size_t part_bytes(int chunk) {
    return (size_t)BATCH * tasks_per_b(chunk) * SLOT_F32 * 4;
}

typedef __bf16 bf16x8 __attribute__((ext_vector_type(8)));
typedef float  f32x4  __attribute__((ext_vector_type(4)));

// ---------------------------------------------------------------------------
// Kernel 1: QKV projection. Grid (128, 3). 256 thr = 4 waves, 128 rows each.
// ---------------------------------------------------------------------------
__global__ __launch_bounds__(256) void qkv_proj(
    const float* __restrict__ x,
    const float* __restrict__ Wq, const float* __restrict__ Wk,
    const float* __restrict__ Wv,
    __bf16* __restrict__ q, __bf16* __restrict__ k, __bf16* __restrict__ v)
{
    __shared__ __align__(16) __bf16 Xl[128][136];
    __shared__ __align__(16) __bf16 Wt[128][136];   // W transposed: Wt[d][c]

    const int t    = threadIdx.x;
    const int lane = t & 63;
    const int w    = t >> 6;
    const int l15  = lane & 15;
    const int l4   = lane >> 4;
    const int rowblk = blockIdx.x * 128;
    const int m      = blockIdx.y;

    const float* W  = (m == 0) ? Wq : (m == 1) ? Wk : Wv;
    __bf16*      op = (m == 0) ? q  : (m == 1) ? k  : v;

    #pragma unroll
    for (int i = 0; i < 16; ++i) {
        int idx = i * 256 + t;
        int r   = idx >> 5;
        int c4  = (idx & 31) << 2;
        float4 f = *(const float4*)(x + (size_t)(rowblk + r) * DIM + c4);
        __bf16* dst = &Xl[r][c4];
        dst[0] = (__bf16)f.x; dst[1] = (__bf16)f.y;
        dst[2] = (__bf16)f.z; dst[3] = (__bf16)f.w;
    }
    #pragma unroll
    for (int i = 0; i < 16; ++i) {
        int idx = i * 256 + t;
        int r   = idx >> 5;
        int c4  = (idx & 31) << 2;
        float4 f = *(const float4*)(W + (size_t)r * DIM + c4);
        Wt[c4 + 0][r] = (__bf16)f.x;
        Wt[c4 + 1][r] = (__bf16)f.y;
        Wt[c4 + 2][r] = (__bf16)f.z;
        Wt[c4 + 3][r] = (__bf16)f.w;
    }
    __syncthreads();

    f32x4 acc[2][8];
    #pragma unroll
    for (int a = 0; a < 2; ++a)
        #pragma unroll
        for (int cf = 0; cf < 8; ++cf) acc[a][cf] = (f32x4){0.f, 0.f, 0.f, 0.f};

    #pragma unroll
    for (int kc = 0; kc < 4; ++kc) {
        bf16x8 af0 = *(const bf16x8*)&Xl[w * 32 +      l15][kc * 32 + l4 * 8];
        bf16x8 af1 = *(const bf16x8*)&Xl[w * 32 + 16 + l15][kc * 32 + l4 * 8];
        #pragma unroll
        for (int cf = 0; cf < 8; ++cf) {
            bf16x8 bfr = *(const bf16x8*)&Wt[cf * 16 + l15][kc * 32 + l4 * 8];
            acc[0][cf] = __builtin_amdgcn_mfma_f32_16x16x32_bf16(af0, bfr, acc[0][cf], 0, 0, 0);
            acc[1][cf] = __builtin_amdgcn_mfma_f32_16x16x32_bf16(af1, bfr, acc[1][cf], 0, 0, 0);
        }
    }

    #pragma unroll
    for (int a = 0; a < 2; ++a)
        #pragma unroll
        for (int cf = 0; cf < 8; ++cf)
            #pragma unroll
            for (int r2 = 0; r2 < 4; ++r2) {
                int row = rowblk + w * 32 + a * 16 + l4 * 4 + r2;
                int col = cf * 16 + l15;
                op[(size_t)row * DIM + col] = (__bf16)acc[a][cf][r2];
            }
}

// ---------------------------------------------------------------------------
// Kernel 2: causal flash attention, split-KV. R2's proven 85us structure
// verbatim; ONLY the task decomposition (CHUNK) is templated.
// ---------------------------------------------------------------------------
template <bool SPLIT, int CHUNK>
__global__ __launch_bounds__(256) void attn(
    const __bf16* __restrict__ q, const __bf16* __restrict__ k,
    const __bf16* __restrict__ v, float* __restrict__ out,
    float* __restrict__ part)
{
    constexpr int NG    = 64 / CHUNK;
    constexpr int TASKS = tasks_per_b(CHUNK);

    __shared__ __bf16 Kl[64][136];
    __shared__ __bf16 Vt[128][72];
    __shared__ __bf16 Pl[4][16][72];

    const int t    = threadIdx.x;
    const int lane = t & 63;
    const int w    = t >> 6;
    const int l15  = lane & 15;
    const int l4   = lane >> 4;
    const int b    = blockIdx.y;

    int qt, chunk, nch, slot = 0;
    if (SPLIT) {
        int j = blockIdx.x;                 // 0..TASKS-1
        int g = 0;
        while (g < NG - 1 && j >= CHUNK * (g + 1) * (g + 2) / 2) ++g;
        int r = j - CHUNK * g * (g + 1) / 2;
        nch   = g + 1;
        qt    = CHUNK * g + r / nch;
        chunk = r - (r / nch) * nch;
        slot  = b * TASKS + j;
    } else {
        qt = blockIdx.x; chunk = 0; nch = 1;
    }
    const int qb0 = qt * 64;
    const int jt0 = chunk * CHUNK;
    const int jtE = SPLIT ? min(jt0 + CHUNK, qt + 1) : qt + 1;
    const size_t base = (size_t)b * SEQ * DIM;

    // Q fragments (A-operand layout: row = l15, k = l4*8 + j + 32*dc)
    bf16x8 qf[4];
    {
        const __bf16* qrow = q + base + (size_t)(qb0 + w * 16 + l15) * DIM;
        #pragma unroll
        for (int dc = 0; dc < 4; ++dc)
            qf[dc] = *(const bf16x8*)(qrow + dc * 32 + l4 * 8);
    }

    f32x4 o[8];
    #pragma unroll
    for (int i = 0; i < 8; ++i) o[i] = (f32x4){0.f, 0.f, 0.f, 0.f};
    float mr[4], lr[4];
    #pragma unroll
    for (int r = 0; r < 4; ++r) { mr[r] = -INFINITY; lr[r] = 0.f; }

    const float scale = 0.08838834764831845f;  // 1/sqrt(128)

    for (int jt = jt0; jt < jtE; ++jt) {
        __syncthreads();

        // ---- load K (linear, padded) and V (transposed + chunk-swizzled) ----
        {
            const __bf16* kg = k + base + (size_t)jt * 64 * DIM;
            const __bf16* vg = v + base + (size_t)jt * 64 * DIM;
            int rr = t >> 4;
            int c  = (t & 15) * 8;
            #pragma unroll
            for (int i = 0; i < 4; ++i) {
                int row = i * 16 + rr;
                *(int4*)&Kl[row][c] = *(const int4*)(kg + (size_t)row * DIM + c);
                bf16x8 vv = *(const bf16x8*)(vg + (size_t)row * DIM + c);
                #pragma unroll
                for (int j = 0; j < 8; ++j) {
                    int cc  = c + j;
                    int col = (((row >> 3) ^ ((cc >> 3) & 7)) << 3) | (row & 7);
                    Vt[cc][col] = vv[j];
                }
            }
        }
        __syncthreads();

        // ---- S = Q K^T ----
        f32x4 s[4];
        #pragma unroll
        for (int kc = 0; kc < 4; ++kc) {
            f32x4 acc = (f32x4){0.f, 0.f, 0.f, 0.f};
            #pragma unroll
            for (int dc = 0; dc < 4; ++dc) {
                bf16x8 kf = *(const bf16x8*)&Kl[kc * 16 + l15][dc * 32 + l4 * 8];
                acc = __builtin_amdgcn_mfma_f32_16x16x32_bf16(qf[dc], kf, acc, 0, 0, 0);
            }
            s[kc] = acc;
        }

        // ---- scale + causal mask + online softmax ----
        const bool diag = (jt == qt);
        float rowmax[4];
        #pragma unroll
        for (int r = 0; r < 4; ++r) rowmax[r] = -INFINITY;
        #pragma unroll
        for (int kc = 0; kc < 4; ++kc) {
            int key = jt * 64 + kc * 16 + l15;
            #pragma unroll
            for (int r = 0; r < 4; ++r) {
                float sv = s[kc][r] * scale;
                if (diag) {
                    int qrow = qb0 + w * 16 + l4 * 4 + r;
                    if (key > qrow) sv = -INFINITY;
                }
                s[kc][r] = sv;
                rowmax[r] = fmaxf(rowmax[r], sv);
            }
        }
        #pragma unroll
        for (int r = 0; r < 4; ++r) {
            float x2 = rowmax[r];
            x2 = fmaxf(x2, __shfl_xor(x2, 1));
            x2 = fmaxf(x2, __shfl_xor(x2, 2));
            x2 = fmaxf(x2, __shfl_xor(x2, 4));
            x2 = fmaxf(x2, __shfl_xor(x2, 8));
            rowmax[r] = x2;
        }
        float alpha[4];
        #pragma unroll
        for (int r = 0; r < 4; ++r) {
            float mnew = fmaxf(mr[r], rowmax[r]);
            alpha[r]   = __expf(mr[r] - mnew);
            mr[r]      = mnew;
        }
        float rowsum[4] = {0.f, 0.f, 0.f, 0.f};
        #pragma unroll
        for (int kc = 0; kc < 4; ++kc)
            #pragma unroll
            for (int r = 0; r < 4; ++r) {
                float p = __expf(s[kc][r] - mr[r]);
                s[kc][r] = p;
                rowsum[r] += p;
            }
        #pragma unroll
        for (int r = 0; r < 4; ++r) {
            float x2 = rowsum[r];
            x2 += __shfl_xor(x2, 1);
            x2 += __shfl_xor(x2, 2);
            x2 += __shfl_xor(x2, 4);
            x2 += __shfl_xor(x2, 8);
            lr[r] = lr[r] * alpha[r] + x2;
        }
        #pragma unroll
        for (int df = 0; df < 8; ++df)
            #pragma unroll
            for (int r = 0; r < 4; ++r) o[df][r] *= alpha[r];

        // ---- P -> bf16 A-fragment layout via per-wave LDS ----
        #pragma unroll
        for (int kc = 0; kc < 4; ++kc)
            #pragma unroll
            for (int r = 0; r < 4; ++r)
                Pl[w][l4 * 4 + r][kc * 16 + l15] = (__bf16)s[kc][r];

        // ---- O += P V ----
        #pragma unroll
        for (int pc = 0; pc < 2; ++pc) {
            bf16x8 pa = *(const bf16x8*)&Pl[w][l15][pc * 32 + l4 * 8];
            #pragma unroll
            for (int df = 0; df < 8; ++df) {
                int cc  = df * 16 + l15;
                int kch = (pc * 4 + l4) ^ ((cc >> 3) & 7);
                bf16x8 vf = *(const bf16x8*)&Vt[cc][kch * 8];
                o[df] = __builtin_amdgcn_mfma_f32_16x16x32_bf16(pa, vf, o[df], 0, 0, 0);
            }
        }
    }

    if (!SPLIT || nch == 1) {
        float inv[4];
        #pragma unroll
        for (int r = 0; r < 4; ++r) inv[r] = 1.0f / lr[r];
        float* op = out + base;
        #pragma unroll
        for (int df = 0; df < 8; ++df)
            #pragma unroll
            for (int r = 0; r < 4; ++r) {
                int row = qb0 + w * 16 + l4 * 4 + r;
                op[(size_t)row * DIM + df * 16 + l15] = o[df][r] * inv[r];
            }
    } else {
        float* sp = part + (size_t)slot * SLOT_F32;
        #pragma unroll
        for (int r = 0; r < 4; ++r) {
            int rl = w * 16 + l4 * 4 + r;
            if (l15 == 0) { sp[rl] = mr[r]; sp[64 + rl] = lr[r]; }
        }
        #pragma unroll
        for (int df = 0; df < 8; ++df)
            #pragma unroll
            for (int r = 0; r < 4; ++r) {
                int rl = w * 16 + l4 * 4 + r;
                sp[128 + (size_t)rl * 128 + df * 16 + l15] = o[df][r];
            }
    }
}

// ---------------------------------------------------------------------------
// Kernel 3: combine partials for qt >= CHUNK. Grid (64-CHUNK, B), 256 thr.
// ---------------------------------------------------------------------------
template <int CHUNK>
__global__ __launch_bounds__(256) void combine(
    const float* __restrict__ part, float* __restrict__ out)
{
    constexpr int TASKS = tasks_per_b(CHUNK);

    const int qt  = blockIdx.x + CHUNK;
    const int b   = blockIdx.y;
    const int g   = qt / CHUNK;
    const int nch = g + 1;
    const int slot0 = b * TASKS + CHUNK * g * (g + 1) / 2 + (qt % CHUNK) * nch;

    const int t   = threadIdx.x;
    const int row = t >> 2;
    const int c0  = (t & 3) * 32;

    float M = -INFINITY;
    for (int c = 0; c < nch; ++c)
        M = fmaxf(M, part[(size_t)(slot0 + c) * SLOT_F32 + row]);
    float L = 0.f;
    for (int c = 0; c < nch; ++c) {
        const float* sp = part + (size_t)(slot0 + c) * SLOT_F32;
        L += sp[64 + row] * __expf(sp[row] - M);
    }

    float4 acc[8];
    #pragma unroll
    for (int i = 0; i < 8; ++i) acc[i] = (float4){0.f, 0.f, 0.f, 0.f};
    for (int c = 0; c < nch; ++c) {
        const float* sp = part + (size_t)(slot0 + c) * SLOT_F32;
        float wgt = __expf(sp[row] - M);
        const float* op = sp + 128 + (size_t)row * 128 + c0;
        #pragma unroll
        for (int i = 0; i < 8; ++i) {
            float4 f = *(const float4*)(op + i * 4);
            acc[i].x += wgt * f.x; acc[i].y += wgt * f.y;
            acc[i].z += wgt * f.z; acc[i].w += wgt * f.w;
        }
    }
    float invL = 1.0f / L;
    float* o = out + ((size_t)b * SEQ + (size_t)qt * 64 + row) * DIM + c0;
    #pragma unroll
    for (int i = 0; i < 8; ++i) {
        float4 f;
        f.x = acc[i].x * invL; f.y = acc[i].y * invL;
        f.z = acc[i].z * invL; f.w = acc[i].w * invL;
        *(float4*)(o + i * 4) = f;
    }
}

// ---------------------------------------------------------------------------
extern "C" void kernel_launch(void* const* d_in, const int* in_sizes, int n_in,
                              void* d_out, int out_size, void* d_ws, size_t ws_size,
                              hipStream_t stream) {
    const float* x  = (const float*)d_in[0];
    const float* Wq = (const float*)d_in[1];
    const float* Wk = (const float*)d_in[2];
    const float* Wv = (const float*)d_in[3];
    float* out = (float*)d_out;

    __bf16* qw = (__bf16*)d_ws;
    __bf16* kw = qw + (size_t)BATCH * SEQ * DIM;
    __bf16* vw = kw + (size_t)BATCH * SEQ * DIM;
    float*  part = (float*)((char*)d_ws + QKV_BYTES);

    qkv_proj<<<dim3(BATCH * SEQ / 128, 3), 256, 0, stream>>>(x, Wq, Wk, Wv, qw, kw, vw);

    if (ws_size >= QKV_BYTES + part_bytes(4)) {
        // finer split: 2176 blocks, <=4 serial tiles each -> better packing
        attn<true, 4><<<dim3(tasks_per_b(4), BATCH), 256, 0, stream>>>(qw, kw, vw, out, part);
        combine<4><<<dim3(60, BATCH), 256, 0, stream>>>(part, out);
    } else if (ws_size >= QKV_BYTES + part_bytes(8)) {
        // proven R2 configuration
        attn<true, 8><<<dim3(tasks_per_b(8), BATCH), 256, 0, stream>>>(qw, kw, vw, out, part);
        combine<8><<<dim3(56, BATCH), 256, 0, stream>>>(part, out);
    } else {
        attn<false, 8><<<dim3(SEQ / 64, BATCH), 256, 0, stream>>>(qw, kw, vw, out, part);
    }
}

// Round 10
// 101.564 us; speedup vs baseline: 1.1778x; 1.0667x over previous
//
#include <hip/hip_runtime.h>
#include <hip/hip_bf16.h>

// Problem constants
constexpr int BATCH = 4;
constexpr int SEQ   = 4096;
constexpr int DIM   = 128;   // head size

// Split-KV: KV tiles are 64 keys; CHUNK tiles per split block (templated).
constexpr size_t QKV_BYTES = (size_t)3 * BATCH * SEQ * DIM * 2;
// partial slot: m[64] f32, l[64] f32, O[64][128] bf16
constexpr size_t SLOT_BYTES = 64 * 4 + 64 * 4 + 64 * 128 * 2;   // 16896

constexpr int tasks_per_b(int chunk) {
    return chunk * (64 / chunk) * (64 / chunk + 1) / 2;
}
constexpr size_t part_bytes(int chunk) {
    return (size_t)BATCH * tasks_per_b(chunk) * SLOT_BYTES;
}

typedef __bf16 bf16x8 __attribute__((ext_vector_type(8)));
typedef float  f32x4  __attribute__((ext_vector_type(4)));

// ---------------------------------------------------------------------------
// Kernel 1: QKV projection, 64-row blocks. Grid (256, 3) = 768 blocks
// = exactly 3 resident blocks x 256 CUs (LDS 52224 B) -> one balanced round.
// ---------------------------------------------------------------------------
__global__ __launch_bounds__(256) void qkv_proj(
    const float* __restrict__ x,
    const float* __restrict__ Wq, const float* __restrict__ Wk,
    const float* __restrict__ Wv,
    __bf16* __restrict__ q, __bf16* __restrict__ k, __bf16* __restrict__ v)
{
    __shared__ __align__(16) __bf16 Xl[64][136];
    __shared__ __align__(16) __bf16 Wt[128][136];   // W transposed: Wt[d][c]

    const int t    = threadIdx.x;
    const int lane = t & 63;
    const int w    = t >> 6;
    const int l15  = lane & 15;
    const int l4   = lane >> 4;
    const int rowblk = blockIdx.x * 64;
    const int m      = blockIdx.y;

    const float* W  = (m == 0) ? Wq : (m == 1) ? Wk : Wv;
    __bf16*      op = (m == 0) ? q  : (m == 1) ? k  : v;

    // X tile (64x128 f32) -> bf16 LDS
    #pragma unroll
    for (int i = 0; i < 8; ++i) {
        int idx = i * 256 + t;
        int r   = idx >> 5;
        int c4  = (idx & 31) << 2;
        float4 f = *(const float4*)(x + (size_t)(rowblk + r) * DIM + c4);
        __bf16* dst = &Xl[r][c4];
        dst[0] = (__bf16)f.x; dst[1] = (__bf16)f.y;
        dst[2] = (__bf16)f.z; dst[3] = (__bf16)f.w;
    }
    // W (row-major [c][d]) transposed into Wt[d][c]
    #pragma unroll
    for (int i = 0; i < 16; ++i) {
        int idx = i * 256 + t;
        int r   = idx >> 5;
        int c4  = (idx & 31) << 2;
        float4 f = *(const float4*)(W + (size_t)r * DIM + c4);
        Wt[c4 + 0][r] = (__bf16)f.x;
        Wt[c4 + 1][r] = (__bf16)f.y;
        Wt[c4 + 2][r] = (__bf16)f.z;
        Wt[c4 + 3][r] = (__bf16)f.w;
    }
    __syncthreads();

    // wave w computes rows [w*16, w*16+16)
    f32x4 acc[8];
    #pragma unroll
    for (int cf = 0; cf < 8; ++cf) acc[cf] = (f32x4){0.f, 0.f, 0.f, 0.f};

    #pragma unroll
    for (int kc = 0; kc < 4; ++kc) {
        bf16x8 af = *(const bf16x8*)&Xl[w * 16 + l15][kc * 32 + l4 * 8];
        #pragma unroll
        for (int cf = 0; cf < 8; ++cf) {
            bf16x8 bfr = *(const bf16x8*)&Wt[cf * 16 + l15][kc * 32 + l4 * 8];
            acc[cf] = __builtin_amdgcn_mfma_f32_16x16x32_bf16(af, bfr, acc[cf], 0, 0, 0);
        }
    }

    #pragma unroll
    for (int cf = 0; cf < 8; ++cf)
        #pragma unroll
        for (int r2 = 0; r2 < 4; ++r2) {
            int row = rowblk + w * 16 + l4 * 4 + r2;
            int col = cf * 16 + l15;
            op[(size_t)row * DIM + col] = (__bf16)acc[cf][r2];
        }
}

// ---------------------------------------------------------------------------
// Kernel 2: causal flash attention, split-KV. R2/R9's proven per-tile code
// verbatim. LDS change only: Pl aliases the Kl buffer (Kl dead after QK^T),
// fenced by a third __syncthreads(). 35840 B LDS -> 4 blocks/CU (was 3).
// Partial O stored as bf16 (m/l stay f32).
// ---------------------------------------------------------------------------
template <bool SPLIT, int CHUNK>
__global__ __launch_bounds__(256) void attn(
    const __bf16* __restrict__ q, const __bf16* __restrict__ k,
    const __bf16* __restrict__ v, float* __restrict__ out,
    char* __restrict__ part)
{
    constexpr int NG    = 64 / CHUNK;
    constexpr int TASKS = tasks_per_b(CHUNK);

    __shared__ __align__(16) __bf16 KlBuf[64 * 136];   // Kl in QK^T phase; Pl in PV phase
    __shared__ __align__(16) __bf16 Vt[128][72];

    typedef __bf16 (*KlT)[136];
    typedef __bf16 (*PlT)[16][72];
    KlT Kl = (KlT)KlBuf;            // [64][136]
    PlT Pl = (PlT)KlBuf;            // [4][16][72] = 9216 B, fits in 17408 B

    const int t    = threadIdx.x;
    const int lane = t & 63;
    const int w    = t >> 6;
    const int l15  = lane & 15;
    const int l4   = lane >> 4;
    const int b    = blockIdx.y;

    int qt, chunk, nch, slot = 0;
    if (SPLIT) {
        int j = blockIdx.x;                 // 0..TASKS-1
        int g = 0;
        while (g < NG - 1 && j >= CHUNK * (g + 1) * (g + 2) / 2) ++g;
        int r = j - CHUNK * g * (g + 1) / 2;
        nch   = g + 1;
        qt    = CHUNK * g + r / nch;
        chunk = r - (r / nch) * nch;
        slot  = b * TASKS + j;
    } else {
        qt = blockIdx.x; chunk = 0; nch = 1;
    }
    const int qb0 = qt * 64;
    const int jt0 = chunk * CHUNK;
    const int jtE = SPLIT ? min(jt0 + CHUNK, qt + 1) : qt + 1;
    const size_t base = (size_t)b * SEQ * DIM;

    // Q fragments (A-operand layout: row = l15, k = l4*8 + j + 32*dc)
    bf16x8 qf[4];
    {
        const __bf16* qrow = q + base + (size_t)(qb0 + w * 16 + l15) * DIM;
        #pragma unroll
        for (int dc = 0; dc < 4; ++dc)
            qf[dc] = *(const bf16x8*)(qrow + dc * 32 + l4 * 8);
    }

    f32x4 o[8];
    #pragma unroll
    for (int i = 0; i < 8; ++i) o[i] = (f32x4){0.f, 0.f, 0.f, 0.f};
    float mr[4], lr[4];
    #pragma unroll
    for (int r = 0; r < 4; ++r) { mr[r] = -INFINITY; lr[r] = 0.f; }

    const float scale = 0.08838834764831845f;  // 1/sqrt(128)

    for (int jt = jt0; jt < jtE; ++jt) {
        __syncthreads();   // B1: all waves done with Pl(=KlBuf)/Vt of prev tile

        // ---- load K (linear, padded) and V (transposed + chunk-swizzled) ----
        {
            const __bf16* kg = k + base + (size_t)jt * 64 * DIM;
            const __bf16* vg = v + base + (size_t)jt * 64 * DIM;
            int rr = t >> 4;
            int c  = (t & 15) * 8;
            #pragma unroll
            for (int i = 0; i < 4; ++i) {
                int row = i * 16 + rr;
                *(int4*)&Kl[row][c] = *(const int4*)(kg + (size_t)row * DIM + c);
                bf16x8 vv = *(const bf16x8*)(vg + (size_t)row * DIM + c);
                #pragma unroll
                for (int j = 0; j < 8; ++j) {
                    int cc  = c + j;
                    int col = (((row >> 3) ^ ((cc >> 3) & 7)) << 3) | (row & 7);
                    Vt[cc][col] = vv[j];
                }
            }
        }
        __syncthreads();   // B2: Kl/Vt visible

        // ---- S = Q K^T ----
        f32x4 s[4];
        #pragma unroll
        for (int kc = 0; kc < 4; ++kc) {
            f32x4 acc = (f32x4){0.f, 0.f, 0.f, 0.f};
            #pragma unroll
            for (int dc = 0; dc < 4; ++dc) {
                bf16x8 kf = *(const bf16x8*)&Kl[kc * 16 + l15][dc * 32 + l4 * 8];
                acc = __builtin_amdgcn_mfma_f32_16x16x32_bf16(qf[dc], kf, acc, 0, 0, 0);
            }
            s[kc] = acc;
        }

        // ---- scale + causal mask + online softmax ----
        const bool diag = (jt == qt);
        float rowmax[4];
        #pragma unroll
        for (int r = 0; r < 4; ++r) rowmax[r] = -INFINITY;
        #pragma unroll
        for (int kc = 0; kc < 4; ++kc) {
            int key = jt * 64 + kc * 16 + l15;
            #pragma unroll
            for (int r = 0; r < 4; ++r) {
                float sv = s[kc][r] * scale;
                if (diag) {
                    int qrow = qb0 + w * 16 + l4 * 4 + r;
                    if (key > qrow) sv = -INFINITY;
                }
                s[kc][r] = sv;
                rowmax[r] = fmaxf(rowmax[r], sv);
            }
        }
        #pragma unroll
        for (int r = 0; r < 4; ++r) {
            float x2 = rowmax[r];
            x2 = fmaxf(x2, __shfl_xor(x2, 1));
            x2 = fmaxf(x2, __shfl_xor(x2, 2));
            x2 = fmaxf(x2, __shfl_xor(x2, 4));
            x2 = fmaxf(x2, __shfl_xor(x2, 8));
            rowmax[r] = x2;
        }
        float alpha[4];
        #pragma unroll
        for (int r = 0; r < 4; ++r) {
            float mnew = fmaxf(mr[r], rowmax[r]);
            alpha[r]   = __expf(mr[r] - mnew);
            mr[r]      = mnew;
        }
        float rowsum[4] = {0.f, 0.f, 0.f, 0.f};
        #pragma unroll
        for (int kc = 0; kc < 4; ++kc)
            #pragma unroll
            for (int r = 0; r < 4; ++r) {
                float p = __expf(s[kc][r] - mr[r]);
                s[kc][r] = p;
                rowsum[r] += p;
            }
        #pragma unroll
        for (int r = 0; r < 4; ++r) {
            float x2 = rowsum[r];
            x2 += __shfl_xor(x2, 1);
            x2 += __shfl_xor(x2, 2);
            x2 += __shfl_xor(x2, 4);
            x2 += __shfl_xor(x2, 8);
            lr[r] = lr[r] * alpha[r] + x2;
        }
        #pragma unroll
        for (int df = 0; df < 8; ++df)
            #pragma unroll
            for (int r = 0; r < 4; ++r) o[df][r] *= alpha[r];

        __syncthreads();   // B3: all waves done reading Kl before Pl overwrite

        // ---- P -> bf16 A-fragment layout via per-wave LDS (aliases Kl) ----
        #pragma unroll
        for (int kc = 0; kc < 4; ++kc)
            #pragma unroll
            for (int r = 0; r < 4; ++r)
                Pl[w][l4 * 4 + r][kc * 16 + l15] = (__bf16)s[kc][r];

        // ---- O += P V ----
        #pragma unroll
        for (int pc = 0; pc < 2; ++pc) {
            bf16x8 pa = *(const bf16x8*)&Pl[w][l15][pc * 32 + l4 * 8];
            #pragma unroll
            for (int df = 0; df < 8; ++df) {
                int cc  = df * 16 + l15;
                int kch = (pc * 4 + l4) ^ ((cc >> 3) & 7);
                bf16x8 vf = *(const bf16x8*)&Vt[cc][kch * 8];
                o[df] = __builtin_amdgcn_mfma_f32_16x16x32_bf16(pa, vf, o[df], 0, 0, 0);
            }
        }
    }

    if (!SPLIT || nch == 1) {
        float inv[4];
        #pragma unroll
        for (int r = 0; r < 4; ++r) inv[r] = 1.0f / lr[r];
        float* op = out + base;
        #pragma unroll
        for (int df = 0; df < 8; ++df)
            #pragma unroll
            for (int r = 0; r < 4; ++r) {
                int row = qb0 + w * 16 + l4 * 4 + r;
                op[(size_t)row * DIM + df * 16 + l15] = o[df][r] * inv[r];
            }
    } else {
        char* sp = part + (size_t)slot * SLOT_BYTES;
        float*  smp = (float*)sp;           // m[64]
        float*  slp = (float*)(sp + 256);   // l[64]
        __bf16* sop = (__bf16*)(sp + 512);  // O[64][128] bf16
        #pragma unroll
        for (int r = 0; r < 4; ++r) {
            int rl = w * 16 + l4 * 4 + r;
            if (l15 == 0) { smp[rl] = mr[r]; slp[rl] = lr[r]; }
        }
        #pragma unroll
        for (int df = 0; df < 8; ++df)
            #pragma unroll
            for (int r = 0; r < 4; ++r) {
                int rl = w * 16 + l4 * 4 + r;
                sop[(size_t)rl * 128 + df * 16 + l15] = (__bf16)o[df][r];
            }
    }
}

// ---------------------------------------------------------------------------
// Kernel 3: combine partials for qt >= CHUNK. Grid (64-CHUNK, B), 256 thr.
// Partial O is bf16; m/l are f32.
// ---------------------------------------------------------------------------
template <int CHUNK>
__global__ __launch_bounds__(256) void combine(
    const char* __restrict__ part, float* __restrict__ out)
{
    constexpr int TASKS = tasks_per_b(CHUNK);

    const int qt  = blockIdx.x + CHUNK;
    const int b   = blockIdx.y;
    const int g   = qt / CHUNK;
    const int nch = g + 1;
    const int slot0 = b * TASKS + CHUNK * g * (g + 1) / 2 + (qt % CHUNK) * nch;

    const int t   = threadIdx.x;
    const int row = t >> 2;
    const int c0  = (t & 3) * 32;

    float M = -INFINITY;
    for (int c = 0; c < nch; ++c) {
        const char* sp = part + (size_t)(slot0 + c) * SLOT_BYTES;
        M = fmaxf(M, ((const float*)sp)[row]);
    }
    float L = 0.f;
    for (int c = 0; c < nch; ++c) {
        const char* sp = part + (size_t)(slot0 + c) * SLOT_BYTES;
        L += ((const float*)(sp + 256))[row] * __expf(((const float*)sp)[row] - M);
    }

    float acc[32];
    #pragma unroll
    for (int i = 0; i < 32; ++i) acc[i] = 0.f;
    for (int c = 0; c < nch; ++c) {
        const char* sp = part + (size_t)(slot0 + c) * SLOT_BYTES;
        float wgt = __expf(((const float*)sp)[row] - M);
        const __bf16* op = (const __bf16*)(sp + 512) + (size_t)row * 128 + c0;
        #pragma unroll
        for (int i = 0; i < 4; ++i) {
            bf16x8 vv = *(const bf16x8*)(op + i * 8);
            #pragma unroll
            for (int j = 0; j < 8; ++j)
                acc[i * 8 + j] += wgt * (float)vv[j];
        }
    }
    float invL = 1.0f / L;
    float* o = out + ((size_t)b * SEQ + (size_t)qt * 64 + row) * DIM + c0;
    #pragma unroll
    for (int i = 0; i < 8; ++i) {
        float4 f;
        f.x = acc[i * 4 + 0] * invL; f.y = acc[i * 4 + 1] * invL;
        f.z = acc[i * 4 + 2] * invL; f.w = acc[i * 4 + 3] * invL;
        *(float4*)(o + i * 4) = f;
    }
}

// ---------------------------------------------------------------------------
extern "C" void kernel_launch(void* const* d_in, const int* in_sizes, int n_in,
                              void* d_out, int out_size, void* d_ws, size_t ws_size,
                              hipStream_t stream) {
    const float* x  = (const float*)d_in[0];
    const float* Wq = (const float*)d_in[1];
    const float* Wk = (const float*)d_in[2];
    const float* Wv = (const float*)d_in[3];
    float* out = (float*)d_out;

    __bf16* qw = (__bf16*)d_ws;
    __bf16* kw = qw + (size_t)BATCH * SEQ * DIM;
    __bf16* vw = kw + (size_t)BATCH * SEQ * DIM;
    char*   part = (char*)d_ws + QKV_BYTES;

    qkv_proj<<<dim3(BATCH * SEQ / 64, 3), 256, 0, stream>>>(x, Wq, Wk, Wv, qw, kw, vw);

    if (ws_size >= QKV_BYTES + part_bytes(4)) {
        // fine split: 2176 blocks, <=4 serial tiles each (proven R9 decomposition)
        attn<true, 4><<<dim3(tasks_per_b(4), BATCH), 256, 0, stream>>>(qw, kw, vw, out, part);
        combine<4><<<dim3(60, BATCH), 256, 0, stream>>>(part, out);
    } else if (ws_size >= QKV_BYTES + part_bytes(8)) {
        attn<true, 8><<<dim3(tasks_per_b(8), BATCH), 256, 0, stream>>>(qw, kw, vw, out, part);
        combine<8><<<dim3(56, BATCH), 256, 0, stream>>>(part, out);
    } else {
        attn<false, 8><<<dim3(SEQ / 64, BATCH), 256, 0, stream>>>(qw, kw, vw, out, part);
    }
}

// Round 11
// 93.962 us; speedup vs baseline: 1.2731x; 1.0809x over previous
//
#include <hip/hip_runtime.h>
#include <hip/hip_bf16.h>

// Problem constants
constexpr int BATCH = 4;
constexpr int SEQ   = 4096;
constexpr int DIM   = 128;   // head size

// Split-KV: KV tiles are 64 keys; CHUNK tiles per split block (templated).
constexpr size_t QKV_BYTES = (size_t)3 * BATCH * SEQ * DIM * 2;
// partial slot: m[64] f32, l[64] f32, O[64][128] bf16
constexpr size_t SLOT_BYTES = 64 * 4 + 64 * 4 + 64 * 128 * 2;   // 16896

constexpr int tasks_per_b(int chunk) {
    return chunk * (64 / chunk) * (64 / chunk + 1) / 2;
}
constexpr size_t part_bytes(int chunk) {
    return (size_t)BATCH * tasks_per_b(chunk) * SLOT_BYTES;
}

typedef __bf16 bf16x8 __attribute__((ext_vector_type(8)));
typedef float  f32x4  __attribute__((ext_vector_type(4)));

// ---------------------------------------------------------------------------
// Kernel 1: QKV projection, 64-row blocks. Grid (256, 3) = 768 blocks
// = exactly 3 resident blocks x 256 CUs -> one balanced round.
// ---------------------------------------------------------------------------
__global__ __launch_bounds__(256) void qkv_proj(
    const float* __restrict__ x,
    const float* __restrict__ Wq, const float* __restrict__ Wk,
    const float* __restrict__ Wv,
    __bf16* __restrict__ q, __bf16* __restrict__ k, __bf16* __restrict__ v)
{
    __shared__ __align__(16) __bf16 Xl[64][136];
    __shared__ __align__(16) __bf16 Wt[128][136];   // W transposed: Wt[d][c]

    const int t    = threadIdx.x;
    const int lane = t & 63;
    const int w    = t >> 6;
    const int l15  = lane & 15;
    const int l4   = lane >> 4;
    const int rowblk = blockIdx.x * 64;
    const int m      = blockIdx.y;

    const float* W  = (m == 0) ? Wq : (m == 1) ? Wk : Wv;
    __bf16*      op = (m == 0) ? q  : (m == 1) ? k  : v;

    // X tile (64x128 f32) -> bf16 LDS
    #pragma unroll
    for (int i = 0; i < 8; ++i) {
        int idx = i * 256 + t;
        int r   = idx >> 5;
        int c4  = (idx & 31) << 2;
        float4 f = *(const float4*)(x + (size_t)(rowblk + r) * DIM + c4);
        __bf16* dst = &Xl[r][c4];
        dst[0] = (__bf16)f.x; dst[1] = (__bf16)f.y;
        dst[2] = (__bf16)f.z; dst[3] = (__bf16)f.w;
    }
    // W (row-major [c][d]) transposed into Wt[d][c]
    #pragma unroll
    for (int i = 0; i < 16; ++i) {
        int idx = i * 256 + t;
        int r   = idx >> 5;
        int c4  = (idx & 31) << 2;
        float4 f = *(const float4*)(W + (size_t)r * DIM + c4);
        Wt[c4 + 0][r] = (__bf16)f.x;
        Wt[c4 + 1][r] = (__bf16)f.y;
        Wt[c4 + 2][r] = (__bf16)f.z;
        Wt[c4 + 3][r] = (__bf16)f.w;
    }
    __syncthreads();

    // wave w computes rows [w*16, w*16+16)
    f32x4 acc[8];
    #pragma unroll
    for (int cf = 0; cf < 8; ++cf) acc[cf] = (f32x4){0.f, 0.f, 0.f, 0.f};

    #pragma unroll
    for (int kc = 0; kc < 4; ++kc) {
        bf16x8 af = *(const bf16x8*)&Xl[w * 16 + l15][kc * 32 + l4 * 8];
        #pragma unroll
        for (int cf = 0; cf < 8; ++cf) {
            bf16x8 bfr = *(const bf16x8*)&Wt[cf * 16 + l15][kc * 32 + l4 * 8];
            acc[cf] = __builtin_amdgcn_mfma_f32_16x16x32_bf16(af, bfr, acc[cf], 0, 0, 0);
        }
    }

    #pragma unroll
    for (int cf = 0; cf < 8; ++cf)
        #pragma unroll
        for (int r2 = 0; r2 < 4; ++r2) {
            int row = rowblk + w * 16 + l4 * 4 + r2;
            int col = cf * 16 + l15;
            op[(size_t)row * DIM + col] = (__bf16)acc[cf][r2];
        }
}

// ---------------------------------------------------------------------------
// Kernel 2: causal flash attention, split-KV. R10's structure verbatim
// (Pl aliases Kl, 3 barriers, bf16 O-partials) with ONE change: V staging
// uses the R5/R6-proven pair-packed ushort2 writes (16 ds_write_b32,
// conflict-free 2 lanes/bank) instead of 32 scalar u16 writes (4-way).
// ---------------------------------------------------------------------------
template <bool SPLIT, int CHUNK>
__global__ __launch_bounds__(256) void attn(
    const __bf16* __restrict__ q, const __bf16* __restrict__ k,
    const __bf16* __restrict__ v, float* __restrict__ out,
    char* __restrict__ part)
{
    constexpr int NG    = 64 / CHUNK;
    constexpr int TASKS = tasks_per_b(CHUNK);

    __shared__ __align__(16) __bf16 KlBuf[64 * 136];   // Kl in QK^T phase; Pl in PV phase
    __shared__ __align__(16) __bf16 Vt[128][72];

    typedef __bf16 (*KlT)[136];
    typedef __bf16 (*PlT)[16][72];
    KlT Kl = (KlT)KlBuf;            // [64][136]
    PlT Pl = (PlT)KlBuf;            // [4][16][72] = 9216 B, fits in 17408 B

    const int t    = threadIdx.x;
    const int lane = t & 63;
    const int w    = t >> 6;
    const int l15  = lane & 15;
    const int l4   = lane >> 4;
    const int b    = blockIdx.y;

    int qt, chunk, nch, slot = 0;
    if (SPLIT) {
        int j = blockIdx.x;                 // 0..TASKS-1
        int g = 0;
        while (g < NG - 1 && j >= CHUNK * (g + 1) * (g + 2) / 2) ++g;
        int r = j - CHUNK * g * (g + 1) / 2;
        nch   = g + 1;
        qt    = CHUNK * g + r / nch;
        chunk = r - (r / nch) * nch;
        slot  = b * TASKS + j;
    } else {
        qt = blockIdx.x; chunk = 0; nch = 1;
    }
    const int qb0 = qt * 64;
    const int jt0 = chunk * CHUNK;
    const int jtE = SPLIT ? min(jt0 + CHUNK, qt + 1) : qt + 1;
    const size_t base = (size_t)b * SEQ * DIM;

    // staging geometry
    const int rr = t >> 4;             // 0..15  (K rows)
    const int c  = (t & 15) * 8;       // K d-base
    const int vp = t >> 5;             // 0..7   (V key pair)
    const int vd = (t & 31) * 4;       // V d-base

    // Q fragments (A-operand layout: row = l15, k = l4*8 + j + 32*dc)
    bf16x8 qf[4];
    {
        const __bf16* qrow = q + base + (size_t)(qb0 + w * 16 + l15) * DIM;
        #pragma unroll
        for (int dc = 0; dc < 4; ++dc)
            qf[dc] = *(const bf16x8*)(qrow + dc * 32 + l4 * 8);
    }

    f32x4 o[8];
    #pragma unroll
    for (int i = 0; i < 8; ++i) o[i] = (f32x4){0.f, 0.f, 0.f, 0.f};
    float mr[4], lr[4];
    #pragma unroll
    for (int r = 0; r < 4; ++r) { mr[r] = -INFINITY; lr[r] = 0.f; }

    const float scale = 0.08838834764831845f;  // 1/sqrt(128)

    for (int jt = jt0; jt < jtE; ++jt) {
        __syncthreads();   // B1: all waves done with Pl(=KlBuf)/Vt of prev tile

        // ---- load K (linear, padded) and V (pair-packed transpose) ----
        {
            const __bf16* kg = k + base + (size_t)jt * 64 * DIM;
            const __bf16* vg = v + base + (size_t)jt * 64 * DIM;
            #pragma unroll
            for (int i = 0; i < 4; ++i) {
                int row = i * 16 + rr;
                *(int4*)&Kl[row][c] = *(const int4*)(kg + (size_t)row * DIM + c);
                // V: rows k0, k0+1; 4 d-elements each; pack pairs -> b32 writes
                int k0 = i * 16 + 2 * vp;
                ushort4 va = *(const ushort4*)(vg + (size_t)k0 * DIM + vd);
                ushort4 vb = *(const ushort4*)(vg + (size_t)(k0 + 1) * DIM + vd);
                #pragma unroll
                for (int e = 0; e < 4; ++e) {
                    int cc  = vd + e;                                  // d index
                    int col = (((k0 >> 3) ^ ((cc >> 3) & 7)) << 3) | (k0 & 7);
                    ushort2 pr;
                    pr.x = (&va.x)[e];
                    pr.y = (&vb.x)[e];
                    *(ushort2*)&Vt[cc][col] = pr;
                }
            }
        }
        __syncthreads();   // B2: Kl/Vt visible

        // ---- S = Q K^T ----
        f32x4 s[4];
        #pragma unroll
        for (int kc = 0; kc < 4; ++kc) {
            f32x4 acc = (f32x4){0.f, 0.f, 0.f, 0.f};
            #pragma unroll
            for (int dc = 0; dc < 4; ++dc) {
                bf16x8 kf = *(const bf16x8*)&Kl[kc * 16 + l15][dc * 32 + l4 * 8];
                acc = __builtin_amdgcn_mfma_f32_16x16x32_bf16(qf[dc], kf, acc, 0, 0, 0);
            }
            s[kc] = acc;
        }

        // ---- scale + causal mask + online softmax ----
        const bool diag = (jt == qt);
        float rowmax[4];
        #pragma unroll
        for (int r = 0; r < 4; ++r) rowmax[r] = -INFINITY;
        #pragma unroll
        for (int kc = 0; kc < 4; ++kc) {
            int key = jt * 64 + kc * 16 + l15;
            #pragma unroll
            for (int r = 0; r < 4; ++r) {
                float sv = s[kc][r] * scale;
                if (diag) {
                    int qrow = qb0 + w * 16 + l4 * 4 + r;
                    if (key > qrow) sv = -INFINITY;
                }
                s[kc][r] = sv;
                rowmax[r] = fmaxf(rowmax[r], sv);
            }
        }
        #pragma unroll
        for (int r = 0; r < 4; ++r) {
            float x2 = rowmax[r];
            x2 = fmaxf(x2, __shfl_xor(x2, 1));
            x2 = fmaxf(x2, __shfl_xor(x2, 2));
            x2 = fmaxf(x2, __shfl_xor(x2, 4));
            x2 = fmaxf(x2, __shfl_xor(x2, 8));
            rowmax[r] = x2;
        }
        float alpha[4];
        #pragma unroll
        for (int r = 0; r < 4; ++r) {
            float mnew = fmaxf(mr[r], rowmax[r]);
            alpha[r]   = __expf(mr[r] - mnew);
            mr[r]      = mnew;
        }
        float rowsum[4] = {0.f, 0.f, 0.f, 0.f};
        #pragma unroll
        for (int kc = 0; kc < 4; ++kc)
            #pragma unroll
            for (int r = 0; r < 4; ++r) {
                float p = __expf(s[kc][r] - mr[r]);
                s[kc][r] = p;
                rowsum[r] += p;
            }
        #pragma unroll
        for (int r = 0; r < 4; ++r) {
            float x2 = rowsum[r];
            x2 += __shfl_xor(x2, 1);
            x2 += __shfl_xor(x2, 2);
            x2 += __shfl_xor(x2, 4);
            x2 += __shfl_xor(x2, 8);
            lr[r] = lr[r] * alpha[r] + x2;
        }
        #pragma unroll
        for (int df = 0; df < 8; ++df)
            #pragma unroll
            for (int r = 0; r < 4; ++r) o[df][r] *= alpha[r];

        __syncthreads();   // B3: all waves done reading Kl before Pl overwrite

        // ---- P -> bf16 A-fragment layout via per-wave LDS (aliases Kl) ----
        #pragma unroll
        for (int kc = 0; kc < 4; ++kc)
            #pragma unroll
            for (int r = 0; r < 4; ++r)
                Pl[w][l4 * 4 + r][kc * 16 + l15] = (__bf16)s[kc][r];

        // ---- O += P V ----
        #pragma unroll
        for (int pc = 0; pc < 2; ++pc) {
            bf16x8 pa = *(const bf16x8*)&Pl[w][l15][pc * 32 + l4 * 8];
            #pragma unroll
            for (int df = 0; df < 8; ++df) {
                int cc  = df * 16 + l15;
                int kch = (pc * 4 + l4) ^ ((cc >> 3) & 7);
                bf16x8 vf = *(const bf16x8*)&Vt[cc][kch * 8];
                o[df] = __builtin_amdgcn_mfma_f32_16x16x32_bf16(pa, vf, o[df], 0, 0, 0);
            }
        }
    }

    if (!SPLIT || nch == 1) {
        float inv[4];
        #pragma unroll
        for (int r = 0; r < 4; ++r) inv[r] = 1.0f / lr[r];
        float* op = out + base;
        #pragma unroll
        for (int df = 0; df < 8; ++df)
            #pragma unroll
            for (int r = 0; r < 4; ++r) {
                int row = qb0 + w * 16 + l4 * 4 + r;
                op[(size_t)row * DIM + df * 16 + l15] = o[df][r] * inv[r];
            }
    } else {
        char* sp = part + (size_t)slot * SLOT_BYTES;
        float*  smp = (float*)sp;           // m[64]
        float*  slp = (float*)(sp + 256);   // l[64]
        __bf16* sop = (__bf16*)(sp + 512);  // O[64][128] bf16
        #pragma unroll
        for (int r = 0; r < 4; ++r) {
            int rl = w * 16 + l4 * 4 + r;
            if (l15 == 0) { smp[rl] = mr[r]; slp[rl] = lr[r]; }
        }
        #pragma unroll
        for (int df = 0; df < 8; ++df)
            #pragma unroll
            for (int r = 0; r < 4; ++r) {
                int rl = w * 16 + l4 * 4 + r;
                sop[(size_t)rl * 128 + df * 16 + l15] = (__bf16)o[df][r];
            }
    }
}

// ---------------------------------------------------------------------------
// Kernel 3: combine partials for qt >= CHUNK. Grid (64-CHUNK, B), 256 thr.
// Partial O is bf16; m/l are f32.
// ---------------------------------------------------------------------------
template <int CHUNK>
__global__ __launch_bounds__(256) void combine(
    const char* __restrict__ part, float* __restrict__ out)
{
    constexpr int TASKS = tasks_per_b(CHUNK);

    const int qt  = blockIdx.x + CHUNK;
    const int b   = blockIdx.y;
    const int g   = qt / CHUNK;
    const int nch = g + 1;
    const int slot0 = b * TASKS + CHUNK * g * (g + 1) / 2 + (qt % CHUNK) * nch;

    const int t   = threadIdx.x;
    const int row = t >> 2;
    const int c0  = (t & 3) * 32;

    float M = -INFINITY;
    for (int c = 0; c < nch; ++c) {
        const char* sp = part + (size_t)(slot0 + c) * SLOT_BYTES;
        M = fmaxf(M, ((const float*)sp)[row]);
    }
    float L = 0.f;
    for (int c = 0; c < nch; ++c) {
        const char* sp = part + (size_t)(slot0 + c) * SLOT_BYTES;
        L += ((const float*)(sp + 256))[row] * __expf(((const float*)sp)[row] - M);
    }

    float acc[32];
    #pragma unroll
    for (int i = 0; i < 32; ++i) acc[i] = 0.f;
    for (int c = 0; c < nch; ++c) {
        const char* sp = part + (size_t)(slot0 + c) * SLOT_BYTES;
        float wgt = __expf(((const float*)sp)[row] - M);
        const __bf16* op = (const __bf16*)(sp + 512) + (size_t)row * 128 + c0;
        #pragma unroll
        for (int i = 0; i < 4; ++i) {
            bf16x8 vv = *(const bf16x8*)(op + i * 8);
            #pragma unroll
            for (int j = 0; j < 8; ++j)
                acc[i * 8 + j] += wgt * (float)vv[j];
        }
    }
    float invL = 1.0f / L;
    float* o = out + ((size_t)b * SEQ + (size_t)qt * 64 + row) * DIM + c0;
    #pragma unroll
    for (int i = 0; i < 8; ++i) {
        float4 f;
        f.x = acc[i * 4 + 0] * invL; f.y = acc[i * 4 + 1] * invL;
        f.z = acc[i * 4 + 2] * invL; f.w = acc[i * 4 + 3] * invL;
        *(float4*)(o + i * 4) = f;
    }
}

// ---------------------------------------------------------------------------
extern "C" void kernel_launch(void* const* d_in, const int* in_sizes, int n_in,
                              void* d_out, int out_size, void* d_ws, size_t ws_size,
                              hipStream_t stream) {
    const float* x  = (const float*)d_in[0];
    const float* Wq = (const float*)d_in[1];
    const float* Wk = (const float*)d_in[2];
    const float* Wv = (const float*)d_in[3];
    float* out = (float*)d_out;

    __bf16* qw = (__bf16*)d_ws;
    __bf16* kw = qw + (size_t)BATCH * SEQ * DIM;
    __bf16* vw = kw + (size_t)BATCH * SEQ * DIM;
    char*   part = (char*)d_ws + QKV_BYTES;

    qkv_proj<<<dim3(BATCH * SEQ / 64, 3), 256, 0, stream>>>(x, Wq, Wk, Wv, qw, kw, vw);

    if (ws_size >= QKV_BYTES + part_bytes(4)) {
        // fine split: 2176 blocks, <=4 serial tiles each (proven R9 decomposition)
        attn<true, 4><<<dim3(tasks_per_b(4), BATCH), 256, 0, stream>>>(qw, kw, vw, out, part);
        combine<4><<<dim3(60, BATCH), 256, 0, stream>>>(part, out);
    } else if (ws_size >= QKV_BYTES + part_bytes(8)) {
        attn<true, 8><<<dim3(tasks_per_b(8), BATCH), 256, 0, stream>>>(qw, kw, vw, out, part);
        combine<8><<<dim3(56, BATCH), 256, 0, stream>>>(part, out);
    } else {
        attn<false, 8><<<dim3(SEQ / 64, BATCH), 256, 0, stream>>>(qw, kw, vw, out, part);
    }
}

// Round 12
// 91.209 us; speedup vs baseline: 1.3115x; 1.0302x over previous
//
#include <hip/hip_runtime.h>
#include <hip/hip_bf16.h>

// Problem constants
constexpr int BATCH = 4;
constexpr int SEQ   = 4096;
constexpr int DIM   = 128;   // head size

// Split-KV: KV tiles are 64 keys; CHUNK tiles per split block (templated).
constexpr size_t QKV_BYTES = (size_t)3 * BATCH * SEQ * DIM * 2;
// partial slot: m[64] f32, l[64] f32, O[64][128] bf16
constexpr size_t SLOT_BYTES = 64 * 4 + 64 * 4 + 64 * 128 * 2;   // 16896

constexpr int tasks_per_b(int chunk) {
    return chunk * (64 / chunk) * (64 / chunk + 1) / 2;
}
constexpr size_t part_bytes(int chunk) {
    return (size_t)BATCH * tasks_per_b(chunk) * SLOT_BYTES;
}

typedef __bf16 bf16x8 __attribute__((ext_vector_type(8)));
typedef __bf16 bf16x4 __attribute__((ext_vector_type(4)));
typedef float  f32x4  __attribute__((ext_vector_type(4)));

// ---------------------------------------------------------------------------
// Kernel 1: QKV projection, 64-row blocks. Grid (256, 3) = 768 blocks.
// ---------------------------------------------------------------------------
__global__ __launch_bounds__(256) void qkv_proj(
    const float* __restrict__ x,
    const float* __restrict__ Wq, const float* __restrict__ Wk,
    const float* __restrict__ Wv,
    __bf16* __restrict__ q, __bf16* __restrict__ k, __bf16* __restrict__ v)
{
    __shared__ __align__(16) __bf16 Xl[64][136];
    __shared__ __align__(16) __bf16 Wt[128][136];   // W transposed: Wt[d][c]

    const int t    = threadIdx.x;
    const int lane = t & 63;
    const int w    = t >> 6;
    const int l15  = lane & 15;
    const int l4   = lane >> 4;
    const int rowblk = blockIdx.x * 64;
    const int m      = blockIdx.y;

    const float* W  = (m == 0) ? Wq : (m == 1) ? Wk : Wv;
    __bf16*      op = (m == 0) ? q  : (m == 1) ? k  : v;

    #pragma unroll
    for (int i = 0; i < 8; ++i) {
        int idx = i * 256 + t;
        int r   = idx >> 5;
        int c4  = (idx & 31) << 2;
        float4 f = *(const float4*)(x + (size_t)(rowblk + r) * DIM + c4);
        __bf16* dst = &Xl[r][c4];
        dst[0] = (__bf16)f.x; dst[1] = (__bf16)f.y;
        dst[2] = (__bf16)f.z; dst[3] = (__bf16)f.w;
    }
    #pragma unroll
    for (int i = 0; i < 16; ++i) {
        int idx = i * 256 + t;
        int r   = idx >> 5;
        int c4  = (idx & 31) << 2;
        float4 f = *(const float4*)(W + (size_t)r * DIM + c4);
        Wt[c4 + 0][r] = (__bf16)f.x;
        Wt[c4 + 1][r] = (__bf16)f.y;
        Wt[c4 + 2][r] = (__bf16)f.z;
        Wt[c4 + 3][r] = (__bf16)f.w;
    }
    __syncthreads();

    f32x4 acc[8];
    #pragma unroll
    for (int cf = 0; cf < 8; ++cf) acc[cf] = (f32x4){0.f, 0.f, 0.f, 0.f};

    #pragma unroll
    for (int kc = 0; kc < 4; ++kc) {
        bf16x8 af = *(const bf16x8*)&Xl[w * 16 + l15][kc * 32 + l4 * 8];
        #pragma unroll
        for (int cf = 0; cf < 8; ++cf) {
            bf16x8 bfr = *(const bf16x8*)&Wt[cf * 16 + l15][kc * 32 + l4 * 8];
            acc[cf] = __builtin_amdgcn_mfma_f32_16x16x32_bf16(af, bfr, acc[cf], 0, 0, 0);
        }
    }

    #pragma unroll
    for (int cf = 0; cf < 8; ++cf)
        #pragma unroll
        for (int r2 = 0; r2 < 4; ++r2) {
            int row = rowblk + w * 16 + l4 * 4 + r2;
            int col = cf * 16 + l15;
            op[(size_t)row * DIM + col] = (__bf16)acc[cf][r2];
        }
}

// ---------------------------------------------------------------------------
// Kernel 2: causal flash attention, split-KV. R11's structure with:
//  (a) k-permuted P/V layout: pi(k) = (k&15)*4 + (k>>4). P-write becomes
//      4x ds_write_b64 (was 16 scalar u16). V stages pairs (k, k+16),
//      adjacent under pi, same 16x ds_write_b32. PV read code unchanged
//      (sum over k is permutation-invariant when P cols and V rows use
//      the same pi). Mask/softmax operate pre-permutation -- unchanged.
//  (b) T5 s_setprio(1) around both MFMA clusters (m191 attn regime).
// ---------------------------------------------------------------------------
template <bool SPLIT, int CHUNK>
__global__ __launch_bounds__(256) void attn(
    const __bf16* __restrict__ q, const __bf16* __restrict__ k,
    const __bf16* __restrict__ v, float* __restrict__ out,
    char* __restrict__ part)
{
    constexpr int NG    = 64 / CHUNK;
    constexpr int TASKS = tasks_per_b(CHUNK);

    __shared__ __align__(16) __bf16 KlBuf[64 * 136];   // Kl in QK^T phase; Pl in PV phase
    __shared__ __align__(16) __bf16 Vt[128][72];

    typedef __bf16 (*KlT)[136];
    typedef __bf16 (*PlT)[16][72];
    KlT Kl = (KlT)KlBuf;            // [64][136]
    PlT Pl = (PlT)KlBuf;            // [4][16][72] = 9216 B

    const int t    = threadIdx.x;
    const int lane = t & 63;
    const int w    = t >> 6;
    const int l15  = lane & 15;
    const int l4   = lane >> 4;
    const int b    = blockIdx.y;

    int qt, chunk, nch, slot = 0;
    if (SPLIT) {
        int j = blockIdx.x;                 // 0..TASKS-1
        int g = 0;
        while (g < NG - 1 && j >= CHUNK * (g + 1) * (g + 2) / 2) ++g;
        int r = j - CHUNK * g * (g + 1) / 2;
        nch   = g + 1;
        qt    = CHUNK * g + r / nch;
        chunk = r - (r / nch) * nch;
        slot  = b * TASKS + j;
    } else {
        qt = blockIdx.x; chunk = 0; nch = 1;
    }
    const int qb0 = qt * 64;
    const int jt0 = chunk * CHUNK;
    const int jtE = SPLIT ? min(jt0 + CHUNK, qt + 1) : qt + 1;
    const size_t base = (size_t)b * SEQ * DIM;

    // staging geometry
    const int rr = t >> 4;             // 0..15  (K rows)
    const int c  = (t & 15) * 8;       // K d-base
    const int vp = t >> 5;             // 0..7   (V pair id within group)
    const int vd = (t & 31) * 4;       // V d-base

    // Q fragments (A-operand layout: row = l15, k = l4*8 + j + 32*dc)
    bf16x8 qf[4];
    {
        const __bf16* qrow = q + base + (size_t)(qb0 + w * 16 + l15) * DIM;
        #pragma unroll
        for (int dc = 0; dc < 4; ++dc)
            qf[dc] = *(const bf16x8*)(qrow + dc * 32 + l4 * 8);
    }

    f32x4 o[8];
    #pragma unroll
    for (int i = 0; i < 8; ++i) o[i] = (f32x4){0.f, 0.f, 0.f, 0.f};
    float mr[4], lr[4];
    #pragma unroll
    for (int r = 0; r < 4; ++r) { mr[r] = -INFINITY; lr[r] = 0.f; }

    const float scale = 0.08838834764831845f;  // 1/sqrt(128)

    for (int jt = jt0; jt < jtE; ++jt) {
        __syncthreads();   // B1: all waves done with Pl(=KlBuf)/Vt of prev tile

        // ---- load K (linear, padded) and V (pi-permuted pair-packed) ----
        {
            const __bf16* kg = k + base + (size_t)jt * 64 * DIM;
            const __bf16* vg = v + base + (size_t)jt * 64 * DIM;
            #pragma unroll
            for (int i = 0; i < 4; ++i) {
                int row = i * 16 + rr;
                *(int4*)&Kl[row][c] = *(const int4*)(kg + (size_t)row * DIM + c);
                // V: pair (ka, ka+16) -> adjacent new indices (kn, kn+1)
                int p    = i * 8 + vp;        // pair id 0..31
                int l15_ = p >> 1;
                int kcp  = p & 1;
                int ka   = 32 * kcp + l15_;   // old key (even new slot)
                int kn   = 4 * l15_ + 2 * kcp;// permuted index, even
                ushort4 va = *(const ushort4*)(vg + (size_t)ka * DIM + vd);
                ushort4 vb = *(const ushort4*)(vg + (size_t)(ka + 16) * DIM + vd);
                #pragma unroll
                for (int e = 0; e < 4; ++e) {
                    int cc  = vd + e;                                  // d index
                    int col = (((kn >> 3) ^ ((cc >> 3) & 7)) << 3) | (kn & 7);
                    ushort2 pr;
                    pr.x = (&va.x)[e];
                    pr.y = (&vb.x)[e];
                    *(ushort2*)&Vt[cc][col] = pr;
                }
            }
        }
        __syncthreads();   // B2: Kl/Vt visible

        // ---- S = Q K^T ----
        f32x4 s[4];
        __builtin_amdgcn_s_setprio(1);
        #pragma unroll
        for (int kc = 0; kc < 4; ++kc) {
            f32x4 acc = (f32x4){0.f, 0.f, 0.f, 0.f};
            #pragma unroll
            for (int dc = 0; dc < 4; ++dc) {
                bf16x8 kf = *(const bf16x8*)&Kl[kc * 16 + l15][dc * 32 + l4 * 8];
                acc = __builtin_amdgcn_mfma_f32_16x16x32_bf16(qf[dc], kf, acc, 0, 0, 0);
            }
            s[kc] = acc;
        }
        __builtin_amdgcn_s_setprio(0);

        // ---- scale + causal mask + online softmax ----
        const bool diag = (jt == qt);
        float rowmax[4];
        #pragma unroll
        for (int r = 0; r < 4; ++r) rowmax[r] = -INFINITY;
        #pragma unroll
        for (int kc = 0; kc < 4; ++kc) {
            int key = jt * 64 + kc * 16 + l15;
            #pragma unroll
            for (int r = 0; r < 4; ++r) {
                float sv = s[kc][r] * scale;
                if (diag) {
                    int qrow = qb0 + w * 16 + l4 * 4 + r;
                    if (key > qrow) sv = -INFINITY;
                }
                s[kc][r] = sv;
                rowmax[r] = fmaxf(rowmax[r], sv);
            }
        }
        #pragma unroll
        for (int r = 0; r < 4; ++r) {
            float x2 = rowmax[r];
            x2 = fmaxf(x2, __shfl_xor(x2, 1));
            x2 = fmaxf(x2, __shfl_xor(x2, 2));
            x2 = fmaxf(x2, __shfl_xor(x2, 4));
            x2 = fmaxf(x2, __shfl_xor(x2, 8));
            rowmax[r] = x2;
        }
        float alpha[4];
        #pragma unroll
        for (int r = 0; r < 4; ++r) {
            float mnew = fmaxf(mr[r], rowmax[r]);
            alpha[r]   = __expf(mr[r] - mnew);
            mr[r]      = mnew;
        }
        float rowsum[4] = {0.f, 0.f, 0.f, 0.f};
        #pragma unroll
        for (int kc = 0; kc < 4; ++kc)
            #pragma unroll
            for (int r = 0; r < 4; ++r) {
                float p = __expf(s[kc][r] - mr[r]);
                s[kc][r] = p;
                rowsum[r] += p;
            }
        #pragma unroll
        for (int r = 0; r < 4; ++r) {
            float x2 = rowsum[r];
            x2 += __shfl_xor(x2, 1);
            x2 += __shfl_xor(x2, 2);
            x2 += __shfl_xor(x2, 4);
            x2 += __shfl_xor(x2, 8);
            lr[r] = lr[r] * alpha[r] + x2;
        }
        #pragma unroll
        for (int df = 0; df < 8; ++df)
            #pragma unroll
            for (int r = 0; r < 4; ++r) o[df][r] *= alpha[r];

        __syncthreads();   // B3: all waves done reading Kl before Pl overwrite

        // ---- P -> Pl in pi-permuted layout: 4x ds_write_b64 ----
        // lane's s[kc][r] belongs at new-col 4*l15 + kc (contiguous in kc)
        #pragma unroll
        for (int r = 0; r < 4; ++r) {
            bf16x4 pk;
            #pragma unroll
            for (int kc = 0; kc < 4; ++kc) pk[kc] = (__bf16)s[kc][r];
            *(bf16x4*)&Pl[w][l4 * 4 + r][l15 * 4] = pk;
        }

        // ---- O += P V (code unchanged; both operands enumerate pi(k)) ----
        __builtin_amdgcn_s_setprio(1);
        #pragma unroll
        for (int pc = 0; pc < 2; ++pc) {
            bf16x8 pa = *(const bf16x8*)&Pl[w][l15][pc * 32 + l4 * 8];
            #pragma unroll
            for (int df = 0; df < 8; ++df) {
                int cc  = df * 16 + l15;
                int kch = (pc * 4 + l4) ^ ((cc >> 3) & 7);
                bf16x8 vf = *(const bf16x8*)&Vt[cc][kch * 8];
                o[df] = __builtin_amdgcn_mfma_f32_16x16x32_bf16(pa, vf, o[df], 0, 0, 0);
            }
        }
        __builtin_amdgcn_s_setprio(0);
    }

    if (!SPLIT || nch == 1) {
        float inv[4];
        #pragma unroll
        for (int r = 0; r < 4; ++r) inv[r] = 1.0f / lr[r];
        float* op = out + base;
        #pragma unroll
        for (int df = 0; df < 8; ++df)
            #pragma unroll
            for (int r = 0; r < 4; ++r) {
                int row = qb0 + w * 16 + l4 * 4 + r;
                op[(size_t)row * DIM + df * 16 + l15] = o[df][r] * inv[r];
            }
    } else {
        char* sp = part + (size_t)slot * SLOT_BYTES;
        float*  smp = (float*)sp;           // m[64]
        float*  slp = (float*)(sp + 256);   // l[64]
        __bf16* sop = (__bf16*)(sp + 512);  // O[64][128] bf16
        #pragma unroll
        for (int r = 0; r < 4; ++r) {
            int rl = w * 16 + l4 * 4 + r;
            if (l15 == 0) { smp[rl] = mr[r]; slp[rl] = lr[r]; }
        }
        #pragma unroll
        for (int df = 0; df < 8; ++df)
            #pragma unroll
            for (int r = 0; r < 4; ++r) {
                int rl = w * 16 + l4 * 4 + r;
                sop[(size_t)rl * 128 + df * 16 + l15] = (__bf16)o[df][r];
            }
    }
}

// ---------------------------------------------------------------------------
// Kernel 3: combine partials for qt >= CHUNK. Grid (64-CHUNK, B), 256 thr.
// ---------------------------------------------------------------------------
template <int CHUNK>
__global__ __launch_bounds__(256) void combine(
    const char* __restrict__ part, float* __restrict__ out)
{
    constexpr int TASKS = tasks_per_b(CHUNK);

    const int qt  = blockIdx.x + CHUNK;
    const int b   = blockIdx.y;
    const int g   = qt / CHUNK;
    const int nch = g + 1;
    const int slot0 = b * TASKS + CHUNK * g * (g + 1) / 2 + (qt % CHUNK) * nch;

    const int t   = threadIdx.x;
    const int row = t >> 2;
    const int c0  = (t & 3) * 32;

    float M = -INFINITY;
    for (int c = 0; c < nch; ++c) {
        const char* sp = part + (size_t)(slot0 + c) * SLOT_BYTES;
        M = fmaxf(M, ((const float*)sp)[row]);
    }
    float L = 0.f;
    for (int c = 0; c < nch; ++c) {
        const char* sp = part + (size_t)(slot0 + c) * SLOT_BYTES;
        L += ((const float*)(sp + 256))[row] * __expf(((const float*)sp)[row] - M);
    }

    float acc[32];
    #pragma unroll
    for (int i = 0; i < 32; ++i) acc[i] = 0.f;
    for (int c = 0; c < nch; ++c) {
        const char* sp = part + (size_t)(slot0 + c) * SLOT_BYTES;
        float wgt = __expf(((const float*)sp)[row] - M);
        const __bf16* op = (const __bf16*)(sp + 512) + (size_t)row * 128 + c0;
        #pragma unroll
        for (int i = 0; i < 4; ++i) {
            bf16x8 vv = *(const bf16x8*)(op + i * 8);
            #pragma unroll
            for (int j = 0; j < 8; ++j)
                acc[i * 8 + j] += wgt * (float)vv[j];
        }
    }
    float invL = 1.0f / L;
    float* o = out + ((size_t)b * SEQ + (size_t)qt * 64 + row) * DIM + c0;
    #pragma unroll
    for (int i = 0; i < 8; ++i) {
        float4 f;
        f.x = acc[i * 4 + 0] * invL; f.y = acc[i * 4 + 1] * invL;
        f.z = acc[i * 4 + 2] * invL; f.w = acc[i * 4 + 3] * invL;
        *(float4*)(o + i * 4) = f;
    }
}

// ---------------------------------------------------------------------------
extern "C" void kernel_launch(void* const* d_in, const int* in_sizes, int n_in,
                              void* d_out, int out_size, void* d_ws, size_t ws_size,
                              hipStream_t stream) {
    const float* x  = (const float*)d_in[0];
    const float* Wq = (const float*)d_in[1];
    const float* Wk = (const float*)d_in[2];
    const float* Wv = (const float*)d_in[3];
    float* out = (float*)d_out;

    __bf16* qw = (__bf16*)d_ws;
    __bf16* kw = qw + (size_t)BATCH * SEQ * DIM;
    __bf16* vw = kw + (size_t)BATCH * SEQ * DIM;
    char*   part = (char*)d_ws + QKV_BYTES;

    qkv_proj<<<dim3(BATCH * SEQ / 64, 3), 256, 0, stream>>>(x, Wq, Wk, Wv, qw, kw, vw);

    if (ws_size >= QKV_BYTES + part_bytes(4)) {
        attn<true, 4><<<dim3(tasks_per_b(4), BATCH), 256, 0, stream>>>(qw, kw, vw, out, part);
        combine<4><<<dim3(60, BATCH), 256, 0, stream>>>(part, out);
    } else if (ws_size >= QKV_BYTES + part_bytes(8)) {
        attn<true, 8><<<dim3(tasks_per_b(8), BATCH), 256, 0, stream>>>(qw, kw, vw, out, part);
        combine<8><<<dim3(56, BATCH), 256, 0, stream>>>(part, out);
    } else {
        attn<false, 8><<<dim3(SEQ / 64, BATCH), 256, 0, stream>>>(qw, kw, vw, out, part);
    }
}